// Round 3
// baseline (633.872 us; speedup 1.0000x reference)
//
#include <hip/hip_runtime.h>

#define NUM_TAGS 128
#define NUM_FEATS 500000
#define BB 64
#define TT 512
#define FF 8

#define SWT_BYTES 128000000ull            // 500000*128*2 (bf16)
#define EM_BYTES  16777216ull             // 64*512*128*4
#define NEED_FULL (SWT_BYTES + EM_BYTES)

typedef __attribute__((ext_vector_type(8))) short short8;
typedef __attribute__((ext_vector_type(4))) float float4v;

__device__ inline unsigned short f2bf(float f) {
  unsigned u = __float_as_uint(f);
  return (unsigned short)((u + 0x7fffu + ((u >> 16) & 1u)) >> 16);
}
__device__ inline float bf2f(unsigned short h) {
  return __uint_as_float(((unsigned)h) << 16);
}

// T1: transpose state_weights [128][500000] fp32 -> swT [500000][128] bf16.
__global__ __launch_bounds__(256) void transpose_kernel(
    const float* __restrict__ sw, unsigned short* __restrict__ swT) {
  __shared__ float tile[32][129];
  const int f0 = blockIdx.x * 32;
  const int t = threadIdx.x;
  const int fi = t & 31, kb = t >> 5;          // kb 0..7
#pragma unroll
  for (int it = 0; it < 16; ++it) {
    int k = kb + it * 8;
    tile[fi][k] = sw[(size_t)k * NUM_FEATS + f0 + fi];  // coalesced 128B
  }
  __syncthreads();
  const int kp = (t & 63) * 2, fo = t >> 6;    // pack 2 bf16 per thread
#pragma unroll
  for (int it = 0; it < 8; ++it) {
    int f2 = fo + it * 4;
    unsigned v = (unsigned)f2bf(tile[f2][kp]) |
                 ((unsigned)f2bf(tile[f2][kp + 1]) << 16);
    *(unsigned*)&swT[(size_t)(f0 + f2) * NUM_TAGS + kp] = v;  // 256B coalesced
  }
}

// K1: emissions from bf16 transposed table (contiguous 256B row per feature),
// exp() folded. em_exp[token][k] = exp(sum_f swT[f][k]).
__global__ __launch_bounds__(128) void gather_t_kernel(
    const int* __restrict__ feats, const unsigned short* __restrict__ swT,
    float* __restrict__ em_exp) {
  const int token = blockIdx.x;
  const int k = threadIdx.x;
  const int* f = feats + token * FF;
  float s = 0.f;
#pragma unroll
  for (int i = 0; i < FF; ++i) s += bf2f(swT[(size_t)f[i] * NUM_TAGS + k]);
  em_exp[(size_t)token * NUM_TAGS + k] = __expf(s);
}

// K1b fallback: direct strided gather from fp32 table.
__global__ __launch_bounds__(128) void gather_f_kernel(
    const int* __restrict__ feats, const float* __restrict__ sw,
    float* __restrict__ em_exp) {
  const int token = blockIdx.x;
  const int k = threadIdx.x;
  const int* f = feats + token * FF;
  const float* row = sw + (size_t)k * NUM_FEATS;
  float s = 0.f;
#pragma unroll
  for (int i = 0; i < FF; ++i) s += row[f[i]];
  em_exp[(size_t)token * NUM_TAGS + k] = __expf(s);
}

// K2: MFMA forward. 16 b per block (4 blocks), 4 waves, wave w owns j-tiles
// {2w,2w+1}. D[j,b] = expT^T[j,i]*alpha[i,b]; expT^T*2^-7 held as bf16 A-frags
// in VGPRs (no LDS traffic); alpha ping-pongs in LDS bf16 [b][i], row stride
// 136 ushorts (272B: 16B-aligned rows, 4b bank skew -> floor-rate b128).
// One barrier per step; ev (exp emissions) prefetched one step ahead.
#define NB 16
#define LROW 136
#define LBUF (NB * LROW)

__global__ __launch_bounds__(256, 1) void fwd_kernel(
    const float* __restrict__ em_exp, const int* __restrict__ tags,
    const float* __restrict__ trans, const float* __restrict__ startT,
    const float* __restrict__ endT, float* __restrict__ out) {
  __shared__ __align__(16) unsigned short abuf[2][LBUF];
  __shared__ float red[16][17];

  const int tid = threadIdx.x;
  const int bl = tid & 15;            // b within block (lane n of B/D)
  const int h = (tid >> 4) & 3;       // lane high bits (K-quad / D row group)
  const int w = tid >> 6;             // wave 0..3
  const int bg = blockIdx.x * NB + bl;

  // A-frags: A[m=lane&15 -> j][k=(lane>>4)*8+jj -> i] = exp(trans[i][j])*2^-7
  short8 afrag[2][4];
#pragma unroll
  for (int mt = 0; mt < 2; ++mt) {
    const int j = (2 * w + mt) * 16 + bl;
#pragma unroll
    for (int kc = 0; kc < 4; ++kc) {
      short8 a;
#pragma unroll
      for (int jj = 0; jj < 8; ++jj) {
        int i = kc * 32 + h * 8 + jj;
        a[jj] = (short)f2bf(__expf(trans[i * NUM_TAGS + j]) * 0.0078125f);
      }
      afrag[mt][kc] = a;
    }
  }

  const float* emb = em_exp + (size_t)bg * TT * NUM_TAGS;

  // alpha_0[b][j] = exp(start[j]) * em_exp[b][0][j]  (unscaled)
  {
    const int jc = tid >> 4, j0 = jc * 8;
#pragma unroll
    for (int jj = 0; jj < 8; ++jj)
      abuf[0][bl * LROW + j0 + jj] =
          f2bf(__expf(startT[j0 + jj]) * emb[j0 + jj]);
  }
  __syncthreads();

  float4v ev[2];
#pragma unroll
  for (int mt = 0; mt < 2; ++mt) {
    int j0 = (2 * w + mt) * 16 + h * 4;
    ev[mt] = *(const float4v*)&emb[(size_t)NUM_TAGS + j0];
  }

  for (int t = 1; t < TT; ++t) {
    const unsigned short* cur = abuf[(t - 1) & 1];
    unsigned short* nxt = abuf[t & 1];

    short8 bfrag[4];
#pragma unroll
    for (int kc = 0; kc < 4; ++kc)
      bfrag[kc] = *(const short8*)&cur[bl * LROW + kc * 32 + h * 8];

    float4v acc0 = {0.f, 0.f, 0.f, 0.f}, acc1 = {0.f, 0.f, 0.f, 0.f};
#pragma unroll
    for (int kc = 0; kc < 4; ++kc) {
      acc0 = __builtin_amdgcn_mfma_f32_16x16x32_bf16(afrag[0][kc], bfrag[kc], acc0, 0, 0, 0);
      acc1 = __builtin_amdgcn_mfma_f32_16x16x32_bf16(afrag[1][kc], bfrag[kc], acc1, 0, 0, 0);
    }

    float4v e0 = ev[0], e1 = ev[1];
    if (t + 1 < TT) {
#pragma unroll
      for (int mt = 0; mt < 2; ++mt) {
        int j0 = (2 * w + mt) * 16 + h * 4;
        ev[mt] = *(const float4v*)&emb[(size_t)(t + 1) * NUM_TAGS + j0];
      }
    }
    {
      int j0 = (2 * w + 0) * 16 + h * 4;   // D rows: j0..j0+3 for col b=bl
      uint2 u;
      u.x = (unsigned)f2bf(acc0[0] * e0[0]) | ((unsigned)f2bf(acc0[1] * e0[1]) << 16);
      u.y = (unsigned)f2bf(acc0[2] * e0[2]) | ((unsigned)f2bf(acc0[3] * e0[3]) << 16);
      *(uint2*)&nxt[bl * LROW + j0] = u;
    }
    {
      int j0 = (2 * w + 1) * 16 + h * 4;
      uint2 u;
      u.x = (unsigned)f2bf(acc1[0] * e1[0]) | ((unsigned)f2bf(acc1[1] * e1[1]) << 16);
      u.y = (unsigned)f2bf(acc1[2] * e1[2]) | ((unsigned)f2bf(acc1[3] * e1[3]) << 16);
      *(uint2*)&nxt[bl * LROW + j0] = u;
    }
    __syncthreads();
  }

  // logZ: sum_j alpha[b][j]*exp(end[j]); alpha_511 is in abuf[1]
  {
    const int jc = tid >> 4, j0 = jc * 8;
    const unsigned short* fin = abuf[(TT - 1) & 1];
    float val = 0.f;
#pragma unroll
    for (int jj = 0; jj < 8; ++jj)
      val += bf2f(fin[bl * LROW + j0 + jj]) * __expf(endT[j0 + jj]);
    red[jc][bl] = val;
  }
  __syncthreads();
  float logzv = 0.f;
  if (tid < 16) {
    float s = 0.f;
#pragma unroll
    for (int q = 0; q < 16; ++q) s += red[q][tid];
    logzv = __logf(s) + 511.0f * 7.0f * 0.69314718055994531f;
  }
  __syncthreads();

  // gold score: thread (bl, seg) covers t in [seg*32, seg*32+32)
  {
    const int seg = tid >> 4;
    const int* tb = tags + (size_t)bg * TT;
    float g = 0.f;
    for (int t = seg * 32; t < seg * 32 + 32; ++t) {
      int tg = tb[t];
      g += __logf(emb[(size_t)t * NUM_TAGS + tg]);
      if (t < TT - 1) g += trans[tg * NUM_TAGS + tb[t + 1]];
    }
    if (seg == 0) g += startT[tb[0]];
    if (seg == 15) g += endT[tb[TT - 1]];
    red[seg][bl] = g;
  }
  __syncthreads();
  if (tid < 16) {
    float s = 0.f;
#pragma unroll
    for (int q = 0; q < 16; ++q) s += red[q][tid];
    out[blockIdx.x * NB + tid] = logzv - s;
  }
}

extern "C" void kernel_launch(void* const* d_in, const int* in_sizes, int n_in,
                              void* d_out, int out_size, void* d_ws, size_t ws_size,
                              hipStream_t stream) {
  const int* feats = (const int*)d_in[0];
  const int* tags = (const int*)d_in[1];
  const float* sw = (const float*)d_in[2];
  const float* trans = (const float*)d_in[3];
  const float* startT = (const float*)d_in[4];
  const float* endT = (const float*)d_in[5];
  float* out = (float*)d_out;

  if (ws_size >= NEED_FULL) {
    unsigned short* swT = (unsigned short*)d_ws;
    float* em_exp = (float*)((char*)d_ws + SWT_BYTES);
    transpose_kernel<<<NUM_FEATS / 32, 256, 0, stream>>>(sw, swT);
    gather_t_kernel<<<BB * TT, 128, 0, stream>>>(feats, swT, em_exp);
    fwd_kernel<<<BB / NB, 256, 0, stream>>>(em_exp, tags, trans, startT, endT, out);
  } else {
    float* em_exp = (float*)d_ws;
    gather_f_kernel<<<BB * TT, 128, 0, stream>>>(feats, sw, em_exp);
    fwd_kernel<<<BB / NB, 256, 0, stream>>>(em_exp, tags, trans, startT, endT, out);
  }
}